// Round 5
// baseline (567.367 us; speedup 1.0000x reference)
//
#include <hip/hip_runtime.h>
#include <stdint.h>

typedef unsigned int u32;
typedef unsigned short ushort_t;

#define T_ 4
#define B_ 16
#define C_ 256
#define N_ 1024
#define CN (C_ * N_)                 /* 262144 */
#define M_ELEMS (64 * C_ * N_)       /* 16777216 elems per [TB,C,N] tensor */

/* workspace byte offsets */
#define OFF_S    0ull                          /* SQ,SK,SV u8: 3*16.7MB */
#define OFF_XC   67108864ull                   /* Xc bf16 [64 tb][16 slab][1024 n][32 k] = 64MB; later aliased by Sc */
#define OFF_SC   67108864ull                   /* Sc bf16 [64 tb][8 kb][1024 n][32 k] = 32MB */
#define OFF_KV   134217728ull                  /* fp32 [64][8][32][32] = 2MB */
#define OFF_BNS  136314880ull                  /* 8KB */
#define OFF_WC   136323072ull                  /* Wc bf16 [3][256][768] = 1.125MB */
#define OFF_WPC  137502720ull                  /* Wpc bf16 [256][512] = 256KB */

typedef __attribute__((ext_vector_type(8))) short bf16x8;
typedef __attribute__((ext_vector_type(4))) float f32x4;

__device__ __forceinline__ ushort_t f2bf(float f) {
  u32 u = __float_as_uint(f);
  u32 r = (u + 0x7FFFu + ((u >> 16) & 1u)) >> 16;
  return (ushort_t)r;
}
__device__ __forceinline__ float bf2f(ushort_t h) { return __uint_as_float((u32)h << 16); }

__device__ __forceinline__ void async_copy16(const void* g, void* l) {
  __builtin_amdgcn_global_load_lds(
      (const __attribute__((address_space(1))) u32*)g,
      (__attribute__((address_space(3))) u32*)l, 16, 0, 0);
}

/* ---- BN coefficient prep ---- */
__global__ void bn_prep(const float* __restrict__ qg, const float* __restrict__ qb2, const float* __restrict__ qm, const float* __restrict__ qv,
                        const float* __restrict__ kg, const float* __restrict__ kb, const float* __restrict__ km, const float* __restrict__ kvv,
                        const float* __restrict__ vg, const float* __restrict__ vb, const float* __restrict__ vm, const float* __restrict__ vv,
                        const float* __restrict__ pbias,
                        const float* __restrict__ pg, const float* __restrict__ pbt, const float* __restrict__ pm, const float* __restrict__ pv,
                        float* __restrict__ bns) {
  int i = threadIdx.x;  /* 1024 threads */
  int br = i >> 8, c = i & 255;
  const float *g, *bt, *m, *v;
  float bias = 0.f;
  if (br == 0)      { g = qg; bt = qb2; m = qm; v = qv; }
  else if (br == 1) { g = kg; bt = kb;  m = km; v = kvv; }
  else if (br == 2) { g = vg; bt = vb;  m = vm; v = vv; }
  else              { g = pg; bt = pbt; m = pm; v = pv; bias = pbias[c]; }
  float sc = g[c] / sqrtf(v[c] + 1e-5f);
  bns[2 * i] = sc;
  bns[2 * i + 1] = bt[c] + (bias - m[c]) * sc;
}

/* ---- split weights to bf16 hi/lo. Wc[br][256][768] = [hi|lo|unused]; Wpc[256][512] = [hi|lo] ---- */
__global__ __launch_bounds__(256) void convert_w(const float* __restrict__ qw, const float* __restrict__ kw,
                                                 const float* __restrict__ vw, const float* __restrict__ pw,
                                                 ushort_t* __restrict__ Wc, ushort_t* __restrict__ Wpc) {
  int id = blockIdx.x * 256 + threadIdx.x;   /* 4*65536 */
  int br = id >> 16, o = (id >> 8) & 255, c = id & 255;
  const float* w = (br == 0) ? qw : (br == 1) ? kw : (br == 2) ? vw : pw;
  float f = w[o * 256 + c];
  ushort_t hi = f2bf(f);
  ushort_t lo = f2bf(f - bf2f(hi));
  if (br < 3) {
    ushort_t* d = Wc + (size_t)br * 196608 + (size_t)o * 768 + c;
    d[0] = hi; d[256] = lo; d[512] = 0;
  } else {
    ushort_t* d = Wpc + (size_t)o * 512 + c;
    d[0] = hi; d[256] = lo;
  }
}

/* ---- x fp32 [tb][256 c][1024 n] -> Xc bf16 [tb][16 slab][1024 n][32 k]; slab kb<8 = hi, 8+kb = lo ---- */
__global__ __launch_bounds__(256) void convert_x(const float* __restrict__ x, ushort_t* __restrict__ Xc) {
  __shared__ ushort_t hi[32][260];
  __shared__ ushort_t lo[32][260];
  int bid = blockIdx.x;
  int nc = bid & 3, kb = (bid >> 2) & 7, tb = bid >> 5;
  int t = threadIdx.x;
  int n0 = nc * 256;
  const float* xb = x + (size_t)tb * CN + (size_t)(kb * 32) * N_ + n0;
#pragma unroll
  for (int p = 0; p < 8; ++p) {
    int k = p * 4 + (t >> 6);
    int n4 = (t & 63) * 4;
    float4 v = *(const float4*)&xb[(size_t)k * N_ + n4];
    ushort_t h0 = f2bf(v.x), h1 = f2bf(v.y), h2 = f2bf(v.z), h3 = f2bf(v.w);
    short4 hv = make_short4((short)h0, (short)h1, (short)h2, (short)h3);
    short4 lv = make_short4((short)f2bf(v.x - bf2f(h0)), (short)f2bf(v.y - bf2f(h1)),
                            (short)f2bf(v.z - bf2f(h2)), (short)f2bf(v.w - bf2f(h3)));
    *(short4*)&hi[k][n4] = hv;
    *(short4*)&lo[k][n4] = lv;
  }
  __syncthreads();
  ushort_t* Hs = Xc + ((size_t)(tb * 16 + kb) * 1024 + n0) * 32;
  ushort_t* Ls = Xc + ((size_t)(tb * 16 + 8 + kb) * 1024 + n0) * 32;
  int kq = t & 3;
#pragma unroll
  for (int q = 0; q < 4; ++q) {
    int n = q * 64 + (t >> 2);
    u32 a0 = (u32)hi[kq * 8 + 0][n] | ((u32)hi[kq * 8 + 1][n] << 16);
    u32 a1 = (u32)hi[kq * 8 + 2][n] | ((u32)hi[kq * 8 + 3][n] << 16);
    u32 a2 = (u32)hi[kq * 8 + 4][n] | ((u32)hi[kq * 8 + 5][n] << 16);
    u32 a3 = (u32)hi[kq * 8 + 6][n] | ((u32)hi[kq * 8 + 7][n] << 16);
    *(uint4*)(Hs + (size_t)n * 32 + kq * 8) = make_uint4(a0, a1, a2, a3);
    u32 b0 = (u32)lo[kq * 8 + 0][n] | ((u32)lo[kq * 8 + 1][n] << 16);
    u32 b1 = (u32)lo[kq * 8 + 2][n] | ((u32)lo[kq * 8 + 3][n] << 16);
    u32 b2 = (u32)lo[kq * 8 + 4][n] | ((u32)lo[kq * 8 + 5][n] << 16);
    u32 b3 = (u32)lo[kq * 8 + 6][n] | ((u32)lo[kq * 8 + 7][n] << 16);
    *(uint4*)(Ls + (size_t)n * 32 + kq * 8) = make_uint4(b0, b1, b2, b3);
  }
}

/* ---- fused q/k/v MFMA GEMM: 128x128 tile (r2 flow) + conflict-free chunked LDS (r4 layout).
   grid (8 nt, 6 mt, 16 b); 4 waves; wave 64x64 = 4x4 frags of 16x16x32; dual-A (hi+lo). ---- */
__global__ __launch_bounds__(256, 2) void gemm_qkv_lif(
    const ushort_t* __restrict__ Wc, const ushort_t* __restrict__ Xc,
    const float* __restrict__ bns, uint8_t* __restrict__ S) {
  __shared__ ushort_t A0[4096];   /* [4 kq][128 row][8] = 8KB */
  __shared__ ushort_t A1[4096];
  __shared__ ushort_t Bs[4096];   /* [4 kq][128 n][8] = 8KB */
  const int nt = blockIdx.x, mt = blockIdx.y, b = blockIdx.z;
  const int br = mt >> 1, rh = mt & 1;
  const ushort_t* Abase = Wc + (size_t)br * 196608 + (size_t)(rh * 128) * 768;
  const int tid = threadIdx.x;
  const int lane = tid & 63;
  const int quad = lane >> 4, r = lane & 15;
  const int w = tid >> 6;
  const int moff = (w & 1) * 64, noff = (w >> 1) * 64;
  /* staging: chunk c = kq*128 + row; thread stages c0=tid (kq 0..1), c1=tid+256 (kq 2..3) */
  const int srow = tid & 127, skq = tid >> 7;
  const int a_src0 = srow * 768 + skq * 8;          /* + s*32 */
  const int b_src0 = srow * 32 + skq * 8;           /* within slab */
  /* fragment LDS offsets (ushort units): A[m=r][k=quad*8+j] at quad*1024 + row*8 */
  int afo[4], bfo[4];
#pragma unroll
  for (int f = 0; f < 4; ++f) {
    afo[f] = quad * 1024 + (moff + f * 16 + r) * 8;
    bfo[f] = quad * 1024 + (noff + f * 16 + r) * 8;
  }

  float mem[16][4];
#pragma unroll
  for (int f = 0; f < 16; ++f)
#pragma unroll
    for (int rg = 0; rg < 4; ++rg) mem[f][rg] = 0.f;

  for (int t = 0; t < 4; ++t) {
    f32x4 acc[16];
#pragma unroll
    for (int f = 0; f < 16; ++f) acc[f] = (f32x4){0.f, 0.f, 0.f, 0.f};
    const ushort_t* Xtb = Xc + (size_t)(t * 16 + b) * 16 * 32768 + (size_t)(nt * 128) * 32;
    /* phase 1: B = X-hi slab s; A = W-hi and W-lo; 32 MFMA per barrier */
    for (int s = 0; s < 8; ++s) {
      const ushort_t* Ah = Abase + s * 32;
      const ushort_t* Alo = Abase + 256 + s * 32;
      const ushort_t* Bb = Xtb + (size_t)s * 32768;
      async_copy16(Ah + a_src0, &A0[tid * 8]);
      async_copy16(Ah + a_src0 + 16, &A0[(tid + 256) * 8]);
      async_copy16(Alo + a_src0, &A1[tid * 8]);
      async_copy16(Alo + a_src0 + 16, &A1[(tid + 256) * 8]);
      async_copy16(Bb + b_src0, &Bs[tid * 8]);
      async_copy16(Bb + b_src0 + 16, &Bs[(tid + 256) * 8]);
      __syncthreads();
      bf16x8 b0 = *(const bf16x8*)&Bs[bfo[0]];
      bf16x8 b1 = *(const bf16x8*)&Bs[bfo[1]];
      bf16x8 b2 = *(const bf16x8*)&Bs[bfo[2]];
      bf16x8 b3 = *(const bf16x8*)&Bs[bfo[3]];
#pragma unroll
      for (int i = 0; i < 4; ++i) {
        bf16x8 a = *(const bf16x8*)&A0[afo[i]];
        acc[i * 4 + 0] = __builtin_amdgcn_mfma_f32_16x16x32_bf16(a, b0, acc[i * 4 + 0], 0, 0, 0);
        acc[i * 4 + 1] = __builtin_amdgcn_mfma_f32_16x16x32_bf16(a, b1, acc[i * 4 + 1], 0, 0, 0);
        acc[i * 4 + 2] = __builtin_amdgcn_mfma_f32_16x16x32_bf16(a, b2, acc[i * 4 + 2], 0, 0, 0);
        acc[i * 4 + 3] = __builtin_amdgcn_mfma_f32_16x16x32_bf16(a, b3, acc[i * 4 + 3], 0, 0, 0);
      }
#pragma unroll
      for (int i = 0; i < 4; ++i) {
        bf16x8 a = *(const bf16x8*)&A1[afo[i]];
        acc[i * 4 + 0] = __builtin_amdgcn_mfma_f32_16x16x32_bf16(a, b0, acc[i * 4 + 0], 0, 0, 0);
        acc[i * 4 + 1] = __builtin_amdgcn_mfma_f32_16x16x32_bf16(a, b1, acc[i * 4 + 1], 0, 0, 0);
        acc[i * 4 + 2] = __builtin_amdgcn_mfma_f32_16x16x32_bf16(a, b2, acc[i * 4 + 2], 0, 0, 0);
        acc[i * 4 + 3] = __builtin_amdgcn_mfma_f32_16x16x32_bf16(a, b3, acc[i * 4 + 3], 0, 0, 0);
      }
      __syncthreads();
    }
    /* phase 2: B = X-lo slab s; A = W-hi; 16 MFMA per barrier */
    for (int s = 0; s < 8; ++s) {
      const ushort_t* Ah = Abase + s * 32;
      const ushort_t* Bb = Xtb + (size_t)(8 + s) * 32768;
      async_copy16(Ah + a_src0, &A0[tid * 8]);
      async_copy16(Ah + a_src0 + 16, &A0[(tid + 256) * 8]);
      async_copy16(Bb + b_src0, &Bs[tid * 8]);
      async_copy16(Bb + b_src0 + 16, &Bs[(tid + 256) * 8]);
      __syncthreads();
      bf16x8 b0 = *(const bf16x8*)&Bs[bfo[0]];
      bf16x8 b1 = *(const bf16x8*)&Bs[bfo[1]];
      bf16x8 b2 = *(const bf16x8*)&Bs[bfo[2]];
      bf16x8 b3 = *(const bf16x8*)&Bs[bfo[3]];
#pragma unroll
      for (int i = 0; i < 4; ++i) {
        bf16x8 a = *(const bf16x8*)&A0[afo[i]];
        acc[i * 4 + 0] = __builtin_amdgcn_mfma_f32_16x16x32_bf16(a, b0, acc[i * 4 + 0], 0, 0, 0);
        acc[i * 4 + 1] = __builtin_amdgcn_mfma_f32_16x16x32_bf16(a, b1, acc[i * 4 + 1], 0, 0, 0);
        acc[i * 4 + 2] = __builtin_amdgcn_mfma_f32_16x16x32_bf16(a, b2, acc[i * 4 + 2], 0, 0, 0);
        acc[i * 4 + 3] = __builtin_amdgcn_mfma_f32_16x16x32_bf16(a, b3, acc[i * 4 + 3], 0, 0, 0);
      }
      __syncthreads();
    }
    /* epilogue: BN + LIF + spike byte store */
    uint8_t* Sb = S + (size_t)br * M_ELEMS + (size_t)(t * 16 + b) * CN;
#pragma unroll
    for (int i = 0; i < 4; ++i) {
#pragma unroll
      for (int rg = 0; rg < 4; ++rg) {
        int c = rh * 128 + moff + i * 16 + quad * 4 + rg;
        float sc = bns[2 * (br * 256 + c)];
        float sh = bns[2 * (br * 256 + c) + 1];
        uint8_t* row = Sb + (size_t)c * N_ + nt * 128 + noff + r;
#pragma unroll
        for (int j = 0; j < 4; ++j) {
          float y = acc[i * 4 + j][rg] * sc + sh;
          float m = mem[i * 4 + j][rg];
          m += (y - m) * 0.5f;
          uint8_t s = (m >= 1.0f) ? 1 : 0;
          row[j * 16] = s;
          mem[i * 4 + j][rg] = s ? 0.f : m;
        }
      }
    }
  }
}

/* ---- v spikes [T,B,C,N] u8 -> d_out v fp32 [T,B,H,N,D] ---- */
__global__ __launch_bounds__(256) void transpose_v(const uint8_t* __restrict__ SV, float* __restrict__ vout) {
  size_t o4 = ((size_t)blockIdx.x * 256 + threadIdx.x) * 4;
  int dd = (int)(o4 & 31);
  int n = (int)((o4 >> 5) & 1023);
  int h = (int)((o4 >> 15) & 7);
  int tb = (int)(o4 >> 18);
  const uint8_t* src = SV + (size_t)tb * CN + (size_t)(h * 32 + dd) * N_ + n;
  *(float4*)(vout + o4) = make_float4((float)src[0], (float)src[(size_t)N_],
                                      (float)src[2 * (size_t)N_], (float)src[3 * (size_t)N_]);
}

/* ---- kv gram via MFMA: block per (tb,h), 4 waves split N, LDS reduce ---- */
__device__ __forceinline__ bf16x8 unpack_spk(uint2 u) {
  bf16x8 o;
  o[0] = (short)((u.x & 1u) ? 0x3F80 : 0);
  o[1] = (short)(((u.x >> 8) & 1u) ? 0x3F80 : 0);
  o[2] = (short)(((u.x >> 16) & 1u) ? 0x3F80 : 0);
  o[3] = (short)(((u.x >> 24) & 1u) ? 0x3F80 : 0);
  o[4] = (short)((u.y & 1u) ? 0x3F80 : 0);
  o[5] = (short)(((u.y >> 8) & 1u) ? 0x3F80 : 0);
  o[6] = (short)(((u.y >> 16) & 1u) ? 0x3F80 : 0);
  o[7] = (short)(((u.y >> 24) & 1u) ? 0x3F80 : 0);
  return o;
}

__global__ __launch_bounds__(256) void kv_gram(const uint8_t* __restrict__ SK,
                                               const uint8_t* __restrict__ SV,
                                               float* __restrict__ KV) {
  __shared__ float red[4096];
  const int tb = blockIdx.x >> 3, h = blockIdx.x & 7;
  const uint8_t* K = SK + (size_t)tb * CN + (size_t)h * 32 * N_;
  const uint8_t* V = SV + (size_t)tb * CN + (size_t)h * 32 * N_;
  const int tid = threadIdx.x;
  const int w = tid >> 6, lane = tid & 63;
  const int quad = lane >> 4, r = lane & 15;
  f32x4 acc[4];
#pragma unroll
  for (int f = 0; f < 4; ++f) acc[f] = (f32x4){0.f, 0.f, 0.f, 0.f};
#pragma unroll
  for (int ks = 0; ks < 8; ++ks) {
    int n0 = w * 256 + ks * 32 + quad * 8;
    bf16x8 ka = unpack_spk(*(const uint2*)(K + (size_t)r * N_ + n0));
    bf16x8 kb = unpack_spk(*(const uint2*)(K + (size_t)(16 + r) * N_ + n0));
    bf16x8 va = unpack_spk(*(const uint2*)(V + (size_t)r * N_ + n0));
    bf16x8 vb = unpack_spk(*(const uint2*)(V + (size_t)(16 + r) * N_ + n0));
    acc[0] = __builtin_amdgcn_mfma_f32_16x16x32_bf16(ka, va, acc[0], 0, 0, 0);
    acc[1] = __builtin_amdgcn_mfma_f32_16x16x32_bf16(ka, vb, acc[1], 0, 0, 0);
    acc[2] = __builtin_amdgcn_mfma_f32_16x16x32_bf16(kb, va, acc[2], 0, 0, 0);
    acc[3] = __builtin_amdgcn_mfma_f32_16x16x32_bf16(kb, vb, acc[3], 0, 0, 0);
  }
#pragma unroll
  for (int f = 0; f < 4; ++f) {
    int d0 = (f >> 1) * 16 + quad * 4;
    int e = (f & 1) * 16 + r;
#pragma unroll
    for (int rg = 0; rg < 4; ++rg) red[w * 1024 + (d0 + rg) * 32 + e] = acc[f][rg];
  }
  __syncthreads();
  int idx = tid * 4;
  float4 s0 = *(const float4*)&red[idx];
  float4 s1 = *(const float4*)&red[1024 + idx];
  float4 s2 = *(const float4*)&red[2048 + idx];
  float4 s3 = *(const float4*)&red[3072 + idx];
  float4 o = make_float4(s0.x + s1.x + s2.x + s3.x, s0.y + s1.y + s2.y + s3.y,
                         s0.z + s1.z + s2.z + s3.z, s0.w + s1.w + s2.w + s3.w);
  *(float4*)&KV[(size_t)(tb * 8 + h) * 1024 + idx] = o;
}

/* ---- fused attn + LIF(0.5) -> bf16 spikes Sc [tb][8 kb][1024 n][32 k] ---- */
__global__ __launch_bounds__(256) void attn_lif(const uint8_t* __restrict__ SQ,
                                                const float* __restrict__ KV,
                                                ushort_t* __restrict__ Sc) {
  __shared__ float kvs[1024];
  const int bid = blockIdx.x;
  const int nb = bid & 15, h = (bid >> 4) & 7, b = bid >> 7;
  const int n0 = nb * 64;
  const int tid = threadIdx.x;
  const int nl = tid & 63, eg = tid >> 6;
  float mem[8];
#pragma unroll
  for (int j = 0; j < 8; ++j) mem[j] = 0.f;
  for (int t = 0; t < 4; ++t) {
    const float* kvp = KV + (size_t)((t * B_ + b) * 8 + h) * 1024;
    *(float4*)&kvs[tid * 4] = *(const float4*)&kvp[tid * 4];
    __syncthreads();
    const uint8_t* q = SQ + (size_t)(t * B_ + b) * CN + (size_t)h * 32 * N_ + n0 + nl;
    float val[8];
#pragma unroll
    for (int j = 0; j < 8; ++j) val[j] = 0.f;
#pragma unroll 4
    for (int dd = 0; dd < 32; ++dd) {
      float qv = (float)q[(size_t)dd * N_];
#pragma unroll
      for (int j = 0; j < 8; ++j) val[j] += qv * kvs[dd * 32 + eg * 8 + j];
    }
    ushort_t pk[8];
#pragma unroll
    for (int j = 0; j < 8; ++j) {
      float a = val[j] * 0.125f;
      mem[j] += (a - mem[j]) * 0.5f;
      int s = (mem[j] >= 0.5f);
      pk[j] = s ? (ushort_t)0x3F80 : (ushort_t)0;
      if (s) mem[j] = 0.f;
    }
    uint4 o;
    o.x = (u32)pk[0] | ((u32)pk[1] << 16);
    o.y = (u32)pk[2] | ((u32)pk[3] << 16);
    o.z = (u32)pk[4] | ((u32)pk[5] << 16);
    o.w = (u32)pk[6] | ((u32)pk[7] << 16);
    *(uint4*)(Sc + ((size_t)((t * B_ + b) * 8 + h) * 1024 + n0 + nl) * 32 + eg * 8) = o;
    __syncthreads();
  }
}

/* ---- p projection MFMA GEMM: 128x128 tile, dual-A, chunked LDS + BN + final LIF.
   grid (8 nt, 2 mt, 16 b) ---- */
__global__ __launch_bounds__(256, 2) void gemm_p_lif(
    const ushort_t* __restrict__ Wpc, const ushort_t* __restrict__ Sc,
    const float* __restrict__ bns, float* __restrict__ out) {
  __shared__ ushort_t A0[4096];
  __shared__ ushort_t A1[4096];
  __shared__ ushort_t Bs[4096];
  const int nt = blockIdx.x, mt = blockIdx.y, b = blockIdx.z;
  const ushort_t* Abase = Wpc + (size_t)(mt * 128) * 512;
  const int tid = threadIdx.x;
  const int lane = tid & 63;
  const int quad = lane >> 4, r = lane & 15;
  const int w = tid >> 6;
  const int moff = (w & 1) * 64, noff = (w >> 1) * 64;
  const int srow = tid & 127, skq = tid >> 7;
  const int a_src0 = srow * 512 + skq * 8;
  const int b_src0 = srow * 32 + skq * 8;
  int afo[4], bfo[4];
#pragma unroll
  for (int f = 0; f < 4; ++f) {
    afo[f] = quad * 1024 + (moff + f * 16 + r) * 8;
    bfo[f] = quad * 1024 + (noff + f * 16 + r) * 8;
  }

  float mem[16][4];
#pragma unroll
  for (int f = 0; f < 16; ++f)
#pragma unroll
    for (int rg = 0; rg < 4; ++rg) mem[f][rg] = 0.f;

  for (int t = 0; t < 4; ++t) {
    f32x4 acc[16];
#pragma unroll
    for (int f = 0; f < 16; ++f) acc[f] = (f32x4){0.f, 0.f, 0.f, 0.f};
    const ushort_t* Stb = Sc + (size_t)(t * 16 + b) * 8 * 32768 + (size_t)(nt * 128) * 32;
    for (int s = 0; s < 8; ++s) {
      const ushort_t* Ah = Abase + s * 32;
      const ushort_t* Alo = Abase + 256 + s * 32;
      const ushort_t* Bb = Stb + (size_t)s * 32768;
      async_copy16(Ah + a_src0, &A0[tid * 8]);
      async_copy16(Ah + a_src0 + 16, &A0[(tid + 256) * 8]);
      async_copy16(Alo + a_src0, &A1[tid * 8]);
      async_copy16(Alo + a_src0 + 16, &A1[(tid + 256) * 8]);
      async_copy16(Bb + b_src0, &Bs[tid * 8]);
      async_copy16(Bb + b_src0 + 16, &Bs[(tid + 256) * 8]);
      __syncthreads();
      bf16x8 b0 = *(const bf16x8*)&Bs[bfo[0]];
      bf16x8 b1 = *(const bf16x8*)&Bs[bfo[1]];
      bf16x8 b2 = *(const bf16x8*)&Bs[bfo[2]];
      bf16x8 b3 = *(const bf16x8*)&Bs[bfo[3]];
#pragma unroll
      for (int i = 0; i < 4; ++i) {
        bf16x8 a = *(const bf16x8*)&A0[afo[i]];
        acc[i * 4 + 0] = __builtin_amdgcn_mfma_f32_16x16x32_bf16(a, b0, acc[i * 4 + 0], 0, 0, 0);
        acc[i * 4 + 1] = __builtin_amdgcn_mfma_f32_16x16x32_bf16(a, b1, acc[i * 4 + 1], 0, 0, 0);
        acc[i * 4 + 2] = __builtin_amdgcn_mfma_f32_16x16x32_bf16(a, b2, acc[i * 4 + 2], 0, 0, 0);
        acc[i * 4 + 3] = __builtin_amdgcn_mfma_f32_16x16x32_bf16(a, b3, acc[i * 4 + 3], 0, 0, 0);
      }
#pragma unroll
      for (int i = 0; i < 4; ++i) {
        bf16x8 a = *(const bf16x8*)&A1[afo[i]];
        acc[i * 4 + 0] = __builtin_amdgcn_mfma_f32_16x16x32_bf16(a, b0, acc[i * 4 + 0], 0, 0, 0);
        acc[i * 4 + 1] = __builtin_amdgcn_mfma_f32_16x16x32_bf16(a, b1, acc[i * 4 + 1], 0, 0, 0);
        acc[i * 4 + 2] = __builtin_amdgcn_mfma_f32_16x16x32_bf16(a, b2, acc[i * 4 + 2], 0, 0, 0);
        acc[i * 4 + 3] = __builtin_amdgcn_mfma_f32_16x16x32_bf16(a, b3, acc[i * 4 + 3], 0, 0, 0);
      }
      __syncthreads();
    }
    /* epilogue: BN + final LIF(1.0) -> fp32 spikes */
    float* Ob = out + (size_t)(t * 16 + b) * CN;
#pragma unroll
    for (int i = 0; i < 4; ++i) {
#pragma unroll
      for (int rg = 0; rg < 4; ++rg) {
        int c = mt * 128 + moff + i * 16 + quad * 4 + rg;
        float sc = bns[2 * (768 + c)];
        float sh = bns[2 * (768 + c) + 1];
        float* row = Ob + (size_t)c * N_ + nt * 128 + noff + r;
#pragma unroll
        for (int j = 0; j < 4; ++j) {
          float y = acc[i * 4 + j][rg] * sc + sh;
          float m = mem[i * 4 + j][rg];
          m += (y - m) * 0.5f;
          float s = (m >= 1.0f) ? 1.f : 0.f;
          row[j * 16] = s;
          mem[i * 4 + j][rg] = m * (1.f - s);
        }
      }
    }
  }
}

extern "C" void kernel_launch(void* const* d_in, const int* in_sizes, int n_in,
                              void* d_out, int out_size, void* d_ws, size_t ws_size,
                              hipStream_t stream) {
  const float* x   = (const float*)d_in[0];
  const float* qw  = (const float*)d_in[2];
  const float* qg  = (const float*)d_in[3];
  const float* qb  = (const float*)d_in[4];
  const float* qm  = (const float*)d_in[5];
  const float* qv  = (const float*)d_in[6];
  const float* kw  = (const float*)d_in[7];
  const float* kg  = (const float*)d_in[8];
  const float* kb  = (const float*)d_in[9];
  const float* km  = (const float*)d_in[10];
  const float* kvv = (const float*)d_in[11];
  const float* vw  = (const float*)d_in[12];
  const float* vg  = (const float*)d_in[13];
  const float* vb  = (const float*)d_in[14];
  const float* vm  = (const float*)d_in[15];
  const float* vv  = (const float*)d_in[16];
  const float* pw  = (const float*)d_in[17];
  const float* pb  = (const float*)d_in[18];
  const float* pg  = (const float*)d_in[19];
  const float* pbt = (const float*)d_in[20];
  const float* pm  = (const float*)d_in[21];
  const float* pv  = (const float*)d_in[22];

  float* out = (float*)d_out;
  float* vout = out + M_ELEMS;

  uint8_t* ws = (uint8_t*)d_ws;
  uint8_t* S   = ws + OFF_S;          /* SQ | SK | SV */
  ushort_t* Xc = (ushort_t*)(ws + OFF_XC);
  ushort_t* Sc = (ushort_t*)(ws + OFF_SC);
  float* KV    = (float*)(ws + OFF_KV);
  float* BNS   = (float*)(ws + OFF_BNS);
  ushort_t* Wcw = (ushort_t*)(ws + OFF_WC);
  ushort_t* Wpc = (ushort_t*)(ws + OFF_WPC);

  bn_prep<<<dim3(1), dim3(1024), 0, stream>>>(qg, qb, qm, qv, kg, kb, km, kvv,
                                              vg, vb, vm, vv, pb, pg, pbt, pm, pv, BNS);
  convert_w<<<dim3(1024), dim3(256), 0, stream>>>(qw, kw, vw, pw, Wcw, Wpc);
  convert_x<<<dim3(2048), dim3(256), 0, stream>>>(x, Xc);
  gemm_qkv_lif<<<dim3(8, 6, 16), dim3(256), 0, stream>>>(Wcw, Xc, BNS, S);
  transpose_v<<<dim3(16384), dim3(256), 0, stream>>>(S + 2ull * M_ELEMS, vout);
  kv_gram<<<dim3(512), dim3(256), 0, stream>>>(S + 1ull * M_ELEMS, S + 2ull * M_ELEMS, KV);
  attn_lif<<<dim3(2048), dim3(256), 0, stream>>>(S, KV, Sc);
  gemm_p_lif<<<dim3(8, 2, 16), dim3(256), 0, stream>>>(Wpc, Sc, BNS, out);
}

// Round 6
// 497.891 us; speedup vs baseline: 1.1395x; 1.1395x over previous
//
#include <hip/hip_runtime.h>
#include <stdint.h>

typedef unsigned int u32;
typedef unsigned short ushort_t;

#define T_ 4
#define B_ 16
#define C_ 256
#define N_ 1024
#define CN (C_ * N_)                 /* 262144 */
#define M_ELEMS (64 * C_ * N_)       /* 16777216 elems per [TB,C,N] tensor */

/* workspace byte offsets */
#define OFF_S    0ull                          /* SQ,SK,SV u8: 3*16.7MB */
#define OFF_XC   67108864ull                   /* Xc bf16 [64 tb][16 slab][1024 n][32 k] = 64MB; later aliased by Sc */
#define OFF_SC   67108864ull                   /* Sc bf16 [64 tb][8 kb][1024 n][32 k] = 32MB */
#define OFF_KV   134217728ull                  /* fp32 [64][8][32][32] = 2MB */
#define OFF_BNS  136314880ull                  /* 8KB */
#define OFF_WC   136323072ull                  /* Wc bf16 [3][256][768] = 1.125MB */
#define OFF_WPC  137502720ull                  /* Wpc bf16 [256][512] = 256KB */

typedef __attribute__((ext_vector_type(8))) short bf16x8;
typedef __attribute__((ext_vector_type(4))) float f32x4;

__device__ __forceinline__ ushort_t f2bf(float f) {
  u32 u = __float_as_uint(f);
  u32 r = (u + 0x7FFFu + ((u >> 16) & 1u)) >> 16;
  return (ushort_t)r;
}
__device__ __forceinline__ float bf2f(ushort_t h) { return __uint_as_float((u32)h << 16); }

__device__ __forceinline__ void async_copy16(const void* g, void* l) {
  __builtin_amdgcn_global_load_lds(
      (const __attribute__((address_space(1))) u32*)g,
      (__attribute__((address_space(3))) u32*)l, 16, 0, 0);
}

/* ---- BN coefficient prep ---- */
__global__ void bn_prep(const float* __restrict__ qg, const float* __restrict__ qb2, const float* __restrict__ qm, const float* __restrict__ qv,
                        const float* __restrict__ kg, const float* __restrict__ kb, const float* __restrict__ km, const float* __restrict__ kvv,
                        const float* __restrict__ vg, const float* __restrict__ vb, const float* __restrict__ vm, const float* __restrict__ vv,
                        const float* __restrict__ pbias,
                        const float* __restrict__ pg, const float* __restrict__ pbt, const float* __restrict__ pm, const float* __restrict__ pv,
                        float* __restrict__ bns) {
  int i = threadIdx.x;  /* 1024 threads */
  int br = i >> 8, c = i & 255;
  const float *g, *bt, *m, *v;
  float bias = 0.f;
  if (br == 0)      { g = qg; bt = qb2; m = qm; v = qv; }
  else if (br == 1) { g = kg; bt = kb;  m = km; v = kvv; }
  else if (br == 2) { g = vg; bt = vb;  m = vm; v = vv; }
  else              { g = pg; bt = pbt; m = pm; v = pv; bias = pbias[c]; }
  float sc = g[c] / sqrtf(v[c] + 1e-5f);
  bns[2 * i] = sc;
  bns[2 * i + 1] = bt[c] + (bias - m[c]) * sc;
}

/* ---- split weights to bf16 hi/lo. Wc[br][256][768] = [hi|lo|unused]; Wpc[256][512] = [hi|lo] ---- */
__global__ __launch_bounds__(256) void convert_w(const float* __restrict__ qw, const float* __restrict__ kw,
                                                 const float* __restrict__ vw, const float* __restrict__ pw,
                                                 ushort_t* __restrict__ Wc, ushort_t* __restrict__ Wpc) {
  int id = blockIdx.x * 256 + threadIdx.x;   /* 4*65536 */
  int br = id >> 16, o = (id >> 8) & 255, c = id & 255;
  const float* w = (br == 0) ? qw : (br == 1) ? kw : (br == 2) ? vw : pw;
  float f = w[o * 256 + c];
  ushort_t hi = f2bf(f);
  ushort_t lo = f2bf(f - bf2f(hi));
  if (br < 3) {
    ushort_t* d = Wc + (size_t)br * 196608 + (size_t)o * 768 + c;
    d[0] = hi; d[256] = lo; d[512] = 0;
  } else {
    ushort_t* d = Wpc + (size_t)o * 512 + c;
    d[0] = hi; d[256] = lo;
  }
}

/* ---- x fp32 [tb][256 c][1024 n] -> Xc bf16 [tb][16 slab][1024 n][32 k]; slab kb<8 = hi, 8+kb = lo ---- */
__global__ __launch_bounds__(256) void convert_x(const float* __restrict__ x, ushort_t* __restrict__ Xc) {
  __shared__ ushort_t hi[32][260];
  __shared__ ushort_t lo[32][260];
  int bid = blockIdx.x;
  int nc = bid & 3, kb = (bid >> 2) & 7, tb = bid >> 5;
  int t = threadIdx.x;
  int n0 = nc * 256;
  const float* xb = x + (size_t)tb * CN + (size_t)(kb * 32) * N_ + n0;
#pragma unroll
  for (int p = 0; p < 8; ++p) {
    int k = p * 4 + (t >> 6);
    int n4 = (t & 63) * 4;
    float4 v = *(const float4*)&xb[(size_t)k * N_ + n4];
    ushort_t h0 = f2bf(v.x), h1 = f2bf(v.y), h2 = f2bf(v.z), h3 = f2bf(v.w);
    short4 hv = make_short4((short)h0, (short)h1, (short)h2, (short)h3);
    short4 lv = make_short4((short)f2bf(v.x - bf2f(h0)), (short)f2bf(v.y - bf2f(h1)),
                            (short)f2bf(v.z - bf2f(h2)), (short)f2bf(v.w - bf2f(h3)));
    *(short4*)&hi[k][n4] = hv;
    *(short4*)&lo[k][n4] = lv;
  }
  __syncthreads();
  ushort_t* Hs = Xc + ((size_t)(tb * 16 + kb) * 1024 + n0) * 32;
  ushort_t* Ls = Xc + ((size_t)(tb * 16 + 8 + kb) * 1024 + n0) * 32;
  int kq = t & 3;
#pragma unroll
  for (int q = 0; q < 4; ++q) {
    int n = q * 64 + (t >> 2);
    u32 a0 = (u32)hi[kq * 8 + 0][n] | ((u32)hi[kq * 8 + 1][n] << 16);
    u32 a1 = (u32)hi[kq * 8 + 2][n] | ((u32)hi[kq * 8 + 3][n] << 16);
    u32 a2 = (u32)hi[kq * 8 + 4][n] | ((u32)hi[kq * 8 + 5][n] << 16);
    u32 a3 = (u32)hi[kq * 8 + 6][n] | ((u32)hi[kq * 8 + 7][n] << 16);
    *(uint4*)(Hs + (size_t)n * 32 + kq * 8) = make_uint4(a0, a1, a2, a3);
    u32 b0 = (u32)lo[kq * 8 + 0][n] | ((u32)lo[kq * 8 + 1][n] << 16);
    u32 b1 = (u32)lo[kq * 8 + 2][n] | ((u32)lo[kq * 8 + 3][n] << 16);
    u32 b2 = (u32)lo[kq * 8 + 4][n] | ((u32)lo[kq * 8 + 5][n] << 16);
    u32 b3 = (u32)lo[kq * 8 + 6][n] | ((u32)lo[kq * 8 + 7][n] << 16);
    *(uint4*)(Ls + (size_t)n * 32 + kq * 8) = make_uint4(b0, b1, b2, b3);
  }
}

/* ---- fused q/k/v MFMA GEMM: 128x128 tile, 2-slab K-step, XOR-swizzled LDS
   (coalesced staging AND conflict-free reads), LDS-staged spike store.
   grid (8 nt, 6 mt, 16 b); 4 waves; wave 64x64 = 4x4 frags 16x16x32; dual-A. ---- */
__global__ __launch_bounds__(256, 2) void gemm_qkv_lif(
    const ushort_t* __restrict__ Wc, const ushort_t* __restrict__ Xc,
    const float* __restrict__ bns, uint8_t* __restrict__ S) {
  __shared__ ushort_t A0[8192];   /* 2 slabs: [slab][128 row][4 swz-part][8] = 16KB */
  __shared__ ushort_t A1[8192];
  __shared__ ushort_t Bs[8192];   /* also reused as 128x128 u8 spike tile in epilogue */
  const int nt = blockIdx.x, mt = blockIdx.y, b = blockIdx.z;
  const int br = mt >> 1, rh = mt & 1;
  const ushort_t* Abase = Wc + (size_t)br * 196608 + (size_t)(rh * 128) * 768;
  const int tid = threadIdx.x;
  const int lane = tid & 63;
  const int quad = lane >> 4, r = lane & 15;
  const int w = tid >> 6;
  const int moff = (w & 1) * 64, noff = (w >> 1) * 64;
  /* staging: slot s (1024 per buffer) holds chunk (slab=s>>9, row=(s&511)>>2,
     part=(s&3)^((s>>3)&3)). 4 consecutive lanes cover one 64B row (permuted). */
  int a_goff[4], b_goff[4];
#pragma unroll
  for (int c = 0; c < 4; ++c) {
    int slot = tid + c * 256;
    int slab = slot >> 9, ww = slot & 511;
    int srow = ww >> 2, sprt = (ww & 3) ^ ((ww >> 3) & 3);
    a_goff[c] = slab * 32 + srow * 768 + sprt * 8;
    b_goff[c] = slab * 32768 + srow * 32 + sprt * 8;
  }
  /* fragment reads: part quad of row m sits at swz slot quad^((m>>1)&3); for
     m = base16 + r this is quad^((r>>1)&3) -> 2-way bank aliasing only. */
  const int qx = quad ^ ((r >> 1) & 3);
  int afo[4], bfo[4];
#pragma unroll
  for (int f = 0; f < 4; ++f) {
    afo[f] = (moff + f * 16 + r) * 32 + qx * 8;
    bfo[f] = (noff + f * 16 + r) * 32 + qx * 8;
  }

  float mem[16][4];
#pragma unroll
  for (int f = 0; f < 16; ++f)
#pragma unroll
    for (int rg = 0; rg < 4; ++rg) mem[f][rg] = 0.f;

  for (int t = 0; t < 4; ++t) {
    f32x4 acc[16];
#pragma unroll
    for (int f = 0; f < 16; ++f) acc[f] = (f32x4){0.f, 0.f, 0.f, 0.f};
    const ushort_t* Xtb = Xc + (size_t)(t * 16 + b) * 16 * 32768 + (size_t)(nt * 128) * 32;
    /* phase 1: 4 iters x 2 hi-slabs; A = W-hi + W-lo; 64 MFMA per barrier */
    for (int s2 = 0; s2 < 4; ++s2) {
      const ushort_t* Ah = Abase + s2 * 64;
      const ushort_t* Al = Abase + 256 + s2 * 64;
      const ushort_t* Bb = Xtb + (size_t)(2 * s2) * 32768;
#pragma unroll
      for (int c = 0; c < 4; ++c) {
        async_copy16(Ah + a_goff[c], &A0[(tid + c * 256) * 8]);
        async_copy16(Al + a_goff[c], &A1[(tid + c * 256) * 8]);
        async_copy16(Bb + b_goff[c], &Bs[(tid + c * 256) * 8]);
      }
      __syncthreads();
#pragma unroll
      for (int sl = 0; sl < 2; ++sl) {
        bf16x8 b0 = *(const bf16x8*)&Bs[sl * 4096 + bfo[0]];
        bf16x8 b1 = *(const bf16x8*)&Bs[sl * 4096 + bfo[1]];
        bf16x8 b2 = *(const bf16x8*)&Bs[sl * 4096 + bfo[2]];
        bf16x8 b3 = *(const bf16x8*)&Bs[sl * 4096 + bfo[3]];
#pragma unroll
        for (int i = 0; i < 4; ++i) {
          bf16x8 a = *(const bf16x8*)&A0[sl * 4096 + afo[i]];
          acc[i * 4 + 0] = __builtin_amdgcn_mfma_f32_16x16x32_bf16(a, b0, acc[i * 4 + 0], 0, 0, 0);
          acc[i * 4 + 1] = __builtin_amdgcn_mfma_f32_16x16x32_bf16(a, b1, acc[i * 4 + 1], 0, 0, 0);
          acc[i * 4 + 2] = __builtin_amdgcn_mfma_f32_16x16x32_bf16(a, b2, acc[i * 4 + 2], 0, 0, 0);
          acc[i * 4 + 3] = __builtin_amdgcn_mfma_f32_16x16x32_bf16(a, b3, acc[i * 4 + 3], 0, 0, 0);
        }
#pragma unroll
        for (int i = 0; i < 4; ++i) {
          bf16x8 a = *(const bf16x8*)&A1[sl * 4096 + afo[i]];
          acc[i * 4 + 0] = __builtin_amdgcn_mfma_f32_16x16x32_bf16(a, b0, acc[i * 4 + 0], 0, 0, 0);
          acc[i * 4 + 1] = __builtin_amdgcn_mfma_f32_16x16x32_bf16(a, b1, acc[i * 4 + 1], 0, 0, 0);
          acc[i * 4 + 2] = __builtin_amdgcn_mfma_f32_16x16x32_bf16(a, b2, acc[i * 4 + 2], 0, 0, 0);
          acc[i * 4 + 3] = __builtin_amdgcn_mfma_f32_16x16x32_bf16(a, b3, acc[i * 4 + 3], 0, 0, 0);
        }
      }
      __syncthreads();
    }
    /* phase 2: 4 iters x 2 lo-slabs; A = W-hi; 32 MFMA per barrier */
    for (int s2 = 0; s2 < 4; ++s2) {
      const ushort_t* Ah = Abase + s2 * 64;
      const ushort_t* Bb = Xtb + (size_t)(8 + 2 * s2) * 32768;
#pragma unroll
      for (int c = 0; c < 4; ++c) {
        async_copy16(Ah + a_goff[c], &A0[(tid + c * 256) * 8]);
        async_copy16(Bb + b_goff[c], &Bs[(tid + c * 256) * 8]);
      }
      __syncthreads();
#pragma unroll
      for (int sl = 0; sl < 2; ++sl) {
        bf16x8 b0 = *(const bf16x8*)&Bs[sl * 4096 + bfo[0]];
        bf16x8 b1 = *(const bf16x8*)&Bs[sl * 4096 + bfo[1]];
        bf16x8 b2 = *(const bf16x8*)&Bs[sl * 4096 + bfo[2]];
        bf16x8 b3 = *(const bf16x8*)&Bs[sl * 4096 + bfo[3]];
#pragma unroll
        for (int i = 0; i < 4; ++i) {
          bf16x8 a = *(const bf16x8*)&A0[sl * 4096 + afo[i]];
          acc[i * 4 + 0] = __builtin_amdgcn_mfma_f32_16x16x32_bf16(a, b0, acc[i * 4 + 0], 0, 0, 0);
          acc[i * 4 + 1] = __builtin_amdgcn_mfma_f32_16x16x32_bf16(a, b1, acc[i * 4 + 1], 0, 0, 0);
          acc[i * 4 + 2] = __builtin_amdgcn_mfma_f32_16x16x32_bf16(a, b2, acc[i * 4 + 2], 0, 0, 0);
          acc[i * 4 + 3] = __builtin_amdgcn_mfma_f32_16x16x32_bf16(a, b3, acc[i * 4 + 3], 0, 0, 0);
        }
      }
      __syncthreads();
    }
    /* epilogue: BN + LIF into LDS spike tile (reuse Bs), then coalesced stores */
    uint8_t* Stile = (uint8_t*)Bs;
#pragma unroll
    for (int i = 0; i < 4; ++i) {
#pragma unroll
      for (int rg = 0; rg < 4; ++rg) {
        int cl = moff + i * 16 + quad * 4 + rg;
        int c = rh * 128 + cl;
        float sc = bns[2 * (br * 256 + c)];
        float sh = bns[2 * (br * 256 + c) + 1];
#pragma unroll
        for (int j = 0; j < 4; ++j) {
          float y = acc[i * 4 + j][rg] * sc + sh;
          float m = mem[i * 4 + j][rg];
          m += (y - m) * 0.5f;
          uint8_t s = (m >= 1.0f) ? 1 : 0;
          Stile[cl * 128 + noff + r + j * 16] = s;
          mem[i * 4 + j][rg] = s ? 0.f : m;
        }
      }
    }
    __syncthreads();
    {
      uint8_t* Sb = S + (size_t)br * M_ELEMS + (size_t)(t * 16 + b) * CN;
      const int srow2 = tid >> 1, shalf = tid & 1;
      uint8_t* gdst = Sb + (size_t)(rh * 128 + srow2) * N_ + nt * 128 + shalf * 64;
      const uint8_t* lsrc = Stile + srow2 * 128 + shalf * 64;
#pragma unroll
      for (int st = 0; st < 4; ++st)
        *(uint4*)(gdst + st * 16) = *(const uint4*)(lsrc + st * 16);
    }
    __syncthreads();
  }
}

/* ---- v spikes [T,B,C,N] u8 -> d_out v fp32 [T,B,H,N,D] ---- */
__global__ __launch_bounds__(256) void transpose_v(const uint8_t* __restrict__ SV, float* __restrict__ vout) {
  size_t o4 = ((size_t)blockIdx.x * 256 + threadIdx.x) * 4;
  int dd = (int)(o4 & 31);
  int n = (int)((o4 >> 5) & 1023);
  int h = (int)((o4 >> 15) & 7);
  int tb = (int)(o4 >> 18);
  const uint8_t* src = SV + (size_t)tb * CN + (size_t)(h * 32 + dd) * N_ + n;
  *(float4*)(vout + o4) = make_float4((float)src[0], (float)src[(size_t)N_],
                                      (float)src[2 * (size_t)N_], (float)src[3 * (size_t)N_]);
}

/* ---- kv gram via MFMA: block per (tb,h), 4 waves split N, LDS reduce ---- */
__device__ __forceinline__ bf16x8 unpack_spk(uint2 u) {
  bf16x8 o;
  o[0] = (short)((u.x & 1u) ? 0x3F80 : 0);
  o[1] = (short)(((u.x >> 8) & 1u) ? 0x3F80 : 0);
  o[2] = (short)(((u.x >> 16) & 1u) ? 0x3F80 : 0);
  o[3] = (short)(((u.x >> 24) & 1u) ? 0x3F80 : 0);
  o[4] = (short)((u.y & 1u) ? 0x3F80 : 0);
  o[5] = (short)(((u.y >> 8) & 1u) ? 0x3F80 : 0);
  o[6] = (short)(((u.y >> 16) & 1u) ? 0x3F80 : 0);
  o[7] = (short)(((u.y >> 24) & 1u) ? 0x3F80 : 0);
  return o;
}

__global__ __launch_bounds__(256) void kv_gram(const uint8_t* __restrict__ SK,
                                               const uint8_t* __restrict__ SV,
                                               float* __restrict__ KV) {
  __shared__ float red[4096];
  const int tb = blockIdx.x >> 3, h = blockIdx.x & 7;
  const uint8_t* K = SK + (size_t)tb * CN + (size_t)h * 32 * N_;
  const uint8_t* V = SV + (size_t)tb * CN + (size_t)h * 32 * N_;
  const int tid = threadIdx.x;
  const int w = tid >> 6, lane = tid & 63;
  const int quad = lane >> 4, r = lane & 15;
  f32x4 acc[4];
#pragma unroll
  for (int f = 0; f < 4; ++f) acc[f] = (f32x4){0.f, 0.f, 0.f, 0.f};
#pragma unroll
  for (int ks = 0; ks < 8; ++ks) {
    int n0 = w * 256 + ks * 32 + quad * 8;
    bf16x8 ka = unpack_spk(*(const uint2*)(K + (size_t)r * N_ + n0));
    bf16x8 kb = unpack_spk(*(const uint2*)(K + (size_t)(16 + r) * N_ + n0));
    bf16x8 va = unpack_spk(*(const uint2*)(V + (size_t)r * N_ + n0));
    bf16x8 vb = unpack_spk(*(const uint2*)(V + (size_t)(16 + r) * N_ + n0));
    acc[0] = __builtin_amdgcn_mfma_f32_16x16x32_bf16(ka, va, acc[0], 0, 0, 0);
    acc[1] = __builtin_amdgcn_mfma_f32_16x16x32_bf16(ka, vb, acc[1], 0, 0, 0);
    acc[2] = __builtin_amdgcn_mfma_f32_16x16x32_bf16(kb, va, acc[2], 0, 0, 0);
    acc[3] = __builtin_amdgcn_mfma_f32_16x16x32_bf16(kb, vb, acc[3], 0, 0, 0);
  }
#pragma unroll
  for (int f = 0; f < 4; ++f) {
    int d0 = (f >> 1) * 16 + quad * 4;
    int e = (f & 1) * 16 + r;
#pragma unroll
    for (int rg = 0; rg < 4; ++rg) red[w * 1024 + (d0 + rg) * 32 + e] = acc[f][rg];
  }
  __syncthreads();
  int idx = tid * 4;
  float4 s0 = *(const float4*)&red[idx];
  float4 s1 = *(const float4*)&red[1024 + idx];
  float4 s2 = *(const float4*)&red[2048 + idx];
  float4 s3 = *(const float4*)&red[3072 + idx];
  float4 o = make_float4(s0.x + s1.x + s2.x + s3.x, s0.y + s1.y + s2.y + s3.y,
                         s0.z + s1.z + s2.z + s3.z, s0.w + s1.w + s2.w + s3.w);
  *(float4*)&KV[(size_t)(tb * 8 + h) * 1024 + idx] = o;
}

/* ---- fused attn + LIF(0.5) -> bf16 spikes Sc [tb][8 kb][1024 n][32 k] ---- */
__global__ __launch_bounds__(256) void attn_lif(const uint8_t* __restrict__ SQ,
                                                const float* __restrict__ KV,
                                                ushort_t* __restrict__ Sc) {
  __shared__ float kvs[1024];
  const int bid = blockIdx.x;
  const int nb = bid & 15, h = (bid >> 4) & 7, b = bid >> 7;
  const int n0 = nb * 64;
  const int tid = threadIdx.x;
  const int nl = tid & 63, eg = tid >> 6;
  float mem[8];
#pragma unroll
  for (int j = 0; j < 8; ++j) mem[j] = 0.f;
  for (int t = 0; t < 4; ++t) {
    const float* kvp = KV + (size_t)((t * B_ + b) * 8 + h) * 1024;
    *(float4*)&kvs[tid * 4] = *(const float4*)&kvp[tid * 4];
    __syncthreads();
    const uint8_t* q = SQ + (size_t)(t * B_ + b) * CN + (size_t)h * 32 * N_ + n0 + nl;
    float val[8];
#pragma unroll
    for (int j = 0; j < 8; ++j) val[j] = 0.f;
#pragma unroll 4
    for (int dd = 0; dd < 32; ++dd) {
      float qv = (float)q[(size_t)dd * N_];
#pragma unroll
      for (int j = 0; j < 8; ++j) val[j] += qv * kvs[dd * 32 + eg * 8 + j];
    }
    ushort_t pk[8];
#pragma unroll
    for (int j = 0; j < 8; ++j) {
      float a = val[j] * 0.125f;
      mem[j] += (a - mem[j]) * 0.5f;
      int s = (mem[j] >= 0.5f);
      pk[j] = s ? (ushort_t)0x3F80 : (ushort_t)0;
      if (s) mem[j] = 0.f;
    }
    uint4 o;
    o.x = (u32)pk[0] | ((u32)pk[1] << 16);
    o.y = (u32)pk[2] | ((u32)pk[3] << 16);
    o.z = (u32)pk[4] | ((u32)pk[5] << 16);
    o.w = (u32)pk[6] | ((u32)pk[7] << 16);
    *(uint4*)(Sc + ((size_t)((t * B_ + b) * 8 + h) * 1024 + n0 + nl) * 32 + eg * 8) = o;
    __syncthreads();
  }
}

/* ---- p projection MFMA GEMM: 128x128 tile, 2-slab K-step, swizzled LDS,
   dual-A + BN + final LIF -> fp32 spikes. grid (8 nt, 2 mt, 16 b) ---- */
__global__ __launch_bounds__(256, 2) void gemm_p_lif(
    const ushort_t* __restrict__ Wpc, const ushort_t* __restrict__ Sc,
    const float* __restrict__ bns, float* __restrict__ out) {
  __shared__ ushort_t A0[8192];
  __shared__ ushort_t A1[8192];
  __shared__ ushort_t Bs[8192];
  const int nt = blockIdx.x, mt = blockIdx.y, b = blockIdx.z;
  const ushort_t* Abase = Wpc + (size_t)(mt * 128) * 512;
  const int tid = threadIdx.x;
  const int lane = tid & 63;
  const int quad = lane >> 4, r = lane & 15;
  const int w = tid >> 6;
  const int moff = (w & 1) * 64, noff = (w >> 1) * 64;
  int a_goff[4], b_goff[4];
#pragma unroll
  for (int c = 0; c < 4; ++c) {
    int slot = tid + c * 256;
    int slab = slot >> 9, ww = slot & 511;
    int srow = ww >> 2, sprt = (ww & 3) ^ ((ww >> 3) & 3);
    a_goff[c] = slab * 32 + srow * 512 + sprt * 8;
    b_goff[c] = slab * 32768 + srow * 32 + sprt * 8;
  }
  const int qx = quad ^ ((r >> 1) & 3);
  int afo[4], bfo[4];
#pragma unroll
  for (int f = 0; f < 4; ++f) {
    afo[f] = (moff + f * 16 + r) * 32 + qx * 8;
    bfo[f] = (noff + f * 16 + r) * 32 + qx * 8;
  }

  float mem[16][4];
#pragma unroll
  for (int f = 0; f < 16; ++f)
#pragma unroll
    for (int rg = 0; rg < 4; ++rg) mem[f][rg] = 0.f;

  for (int t = 0; t < 4; ++t) {
    f32x4 acc[16];
#pragma unroll
    for (int f = 0; f < 16; ++f) acc[f] = (f32x4){0.f, 0.f, 0.f, 0.f};
    const ushort_t* Stb = Sc + (size_t)(t * 16 + b) * 8 * 32768 + (size_t)(nt * 128) * 32;
    for (int s2 = 0; s2 < 4; ++s2) {
      const ushort_t* Ah = Abase + s2 * 64;
      const ushort_t* Al = Abase + 256 + s2 * 64;
      const ushort_t* Bb = Stb + (size_t)(2 * s2) * 32768;
#pragma unroll
      for (int c = 0; c < 4; ++c) {
        async_copy16(Ah + a_goff[c], &A0[(tid + c * 256) * 8]);
        async_copy16(Al + a_goff[c], &A1[(tid + c * 256) * 8]);
        async_copy16(Bb + b_goff[c], &Bs[(tid + c * 256) * 8]);
      }
      __syncthreads();
#pragma unroll
      for (int sl = 0; sl < 2; ++sl) {
        bf16x8 b0 = *(const bf16x8*)&Bs[sl * 4096 + bfo[0]];
        bf16x8 b1 = *(const bf16x8*)&Bs[sl * 4096 + bfo[1]];
        bf16x8 b2 = *(const bf16x8*)&Bs[sl * 4096 + bfo[2]];
        bf16x8 b3 = *(const bf16x8*)&Bs[sl * 4096 + bfo[3]];
#pragma unroll
        for (int i = 0; i < 4; ++i) {
          bf16x8 a = *(const bf16x8*)&A0[sl * 4096 + afo[i]];
          acc[i * 4 + 0] = __builtin_amdgcn_mfma_f32_16x16x32_bf16(a, b0, acc[i * 4 + 0], 0, 0, 0);
          acc[i * 4 + 1] = __builtin_amdgcn_mfma_f32_16x16x32_bf16(a, b1, acc[i * 4 + 1], 0, 0, 0);
          acc[i * 4 + 2] = __builtin_amdgcn_mfma_f32_16x16x32_bf16(a, b2, acc[i * 4 + 2], 0, 0, 0);
          acc[i * 4 + 3] = __builtin_amdgcn_mfma_f32_16x16x32_bf16(a, b3, acc[i * 4 + 3], 0, 0, 0);
        }
#pragma unroll
        for (int i = 0; i < 4; ++i) {
          bf16x8 a = *(const bf16x8*)&A1[sl * 4096 + afo[i]];
          acc[i * 4 + 0] = __builtin_amdgcn_mfma_f32_16x16x32_bf16(a, b0, acc[i * 4 + 0], 0, 0, 0);
          acc[i * 4 + 1] = __builtin_amdgcn_mfma_f32_16x16x32_bf16(a, b1, acc[i * 4 + 1], 0, 0, 0);
          acc[i * 4 + 2] = __builtin_amdgcn_mfma_f32_16x16x32_bf16(a, b2, acc[i * 4 + 2], 0, 0, 0);
          acc[i * 4 + 3] = __builtin_amdgcn_mfma_f32_16x16x32_bf16(a, b3, acc[i * 4 + 3], 0, 0, 0);
        }
      }
      __syncthreads();
    }
    /* epilogue: BN + final LIF(1.0) -> fp32 spikes (64B-coalesced segments) */
    float* Ob = out + (size_t)(t * 16 + b) * CN;
#pragma unroll
    for (int i = 0; i < 4; ++i) {
#pragma unroll
      for (int rg = 0; rg < 4; ++rg) {
        int c = mt * 128 + moff + i * 16 + quad * 4 + rg;
        float sc = bns[2 * (768 + c)];
        float sh = bns[2 * (768 + c) + 1];
        float* row = Ob + (size_t)c * N_ + nt * 128 + noff + r;
#pragma unroll
        for (int j = 0; j < 4; ++j) {
          float y = acc[i * 4 + j][rg] * sc + sh;
          float m = mem[i * 4 + j][rg];
          m += (y - m) * 0.5f;
          float s = (m >= 1.0f) ? 1.f : 0.f;
          row[j * 16] = s;
          mem[i * 4 + j][rg] = m * (1.f - s);
        }
      }
    }
  }
}

extern "C" void kernel_launch(void* const* d_in, const int* in_sizes, int n_in,
                              void* d_out, int out_size, void* d_ws, size_t ws_size,
                              hipStream_t stream) {
  const float* x   = (const float*)d_in[0];
  const float* qw  = (const float*)d_in[2];
  const float* qg  = (const float*)d_in[3];
  const float* qb  = (const float*)d_in[4];
  const float* qm  = (const float*)d_in[5];
  const float* qv  = (const float*)d_in[6];
  const float* kw  = (const float*)d_in[7];
  const float* kg  = (const float*)d_in[8];
  const float* kb  = (const float*)d_in[9];
  const float* km  = (const float*)d_in[10];
  const float* kvv = (const float*)d_in[11];
  const float* vw  = (const float*)d_in[12];
  const float* vg  = (const float*)d_in[13];
  const float* vb  = (const float*)d_in[14];
  const float* vm  = (const float*)d_in[15];
  const float* vv  = (const float*)d_in[16];
  const float* pw  = (const float*)d_in[17];
  const float* pb  = (const float*)d_in[18];
  const float* pg  = (const float*)d_in[19];
  const float* pbt = (const float*)d_in[20];
  const float* pm  = (const float*)d_in[21];
  const float* pv  = (const float*)d_in[22];

  float* out = (float*)d_out;
  float* vout = out + M_ELEMS;

  uint8_t* ws = (uint8_t*)d_ws;
  uint8_t* S   = ws + OFF_S;          /* SQ | SK | SV */
  ushort_t* Xc = (ushort_t*)(ws + OFF_XC);
  ushort_t* Sc = (ushort_t*)(ws + OFF_SC);
  float* KV    = (float*)(ws + OFF_KV);
  float* BNS   = (float*)(ws + OFF_BNS);
  ushort_t* Wcw = (ushort_t*)(ws + OFF_WC);
  ushort_t* Wpc = (ushort_t*)(ws + OFF_WPC);

  bn_prep<<<dim3(1), dim3(1024), 0, stream>>>(qg, qb, qm, qv, kg, kb, km, kvv,
                                              vg, vb, vm, vv, pb, pg, pbt, pm, pv, BNS);
  convert_w<<<dim3(1024), dim3(256), 0, stream>>>(qw, kw, vw, pw, Wcw, Wpc);
  convert_x<<<dim3(2048), dim3(256), 0, stream>>>(x, Xc);
  gemm_qkv_lif<<<dim3(8, 6, 16), dim3(256), 0, stream>>>(Wcw, Xc, BNS, S);
  transpose_v<<<dim3(16384), dim3(256), 0, stream>>>(S + 2ull * M_ELEMS, vout);
  kv_gram<<<dim3(512), dim3(256), 0, stream>>>(S + 1ull * M_ELEMS, S + 2ull * M_ELEMS, KV);
  attn_lif<<<dim3(2048), dim3(256), 0, stream>>>(S, KV, Sc);
  gemm_p_lif<<<dim3(8, 2, 16), dim3(256), 0, stream>>>(Wpc, Sc, BNS, out);
}